// Round 5
// baseline (112.233 us; speedup 1.0000x reference)
//
#include <hip/hip_runtime.h>
#include <hip/hip_bf16.h>

#define HID   128
#define PNUM  1024
#define LASTB 63
#define BP    (64 * PNUM)   // 65536 points
#define NBLK  512           // all blocks: harm(2 i's) + MLP(128 pts)
#define PPB   128           // points per block
#define WS    136           // LDS row stride in bf16 units (16B-aligned pad)

typedef __attribute__((ext_vector_type(8))) short short8;   // 8 bf16 = 4 VGPRs
typedef __attribute__((ext_vector_type(4))) float f32x4;    // MFMA C/D

__device__ __forceinline__ unsigned short f2bf(float x) {
    unsigned u = __float_as_uint(x);
    return (unsigned short)((u + 0x7FFFu + ((u >> 16) & 1u)) >> 16);
}

__device__ __forceinline__ unsigned pk2(float a, float b) {
    __hip_bfloat162 h = __float22bfloat162_rn(make_float2(a, b));
    union { __hip_bfloat162 h2; unsigned u; } c;
    c.h2 = h;
    return c.u;
}

__device__ __forceinline__ unsigned long long umax64(unsigned long long a,
                                                     unsigned long long b) {
    return a > b ? a : b;
}

// ---------------------------------------------------------------------------
// One kernel, 512 blocks x 256 threads (2 blocks/CU, 69 KB LDS each).
// Uniform per block: stage sf/sm + W2^T/W3^T (bf16) -> harm counts for 2 i's
// -> MFMA MLP for 128 points -> ticket; last block runs the selection.
//   A-frag (h1) in regs: A[m=lane&15][k=quad*8+j]
//   B-frag (W2^T LDS):   B[k=quad*8+j][n=lane&15], WS=136 pad -> 2-way (free)
//   C/D: row=quad*4+reg (point), col=lane&15
//   Layer-3 via per-wave LDS round-trip (C-layout -> A-layout), W3 zero-padded.
// ---------------------------------------------------------------------------
__global__ __launch_bounds__(256) void fused(
    const float* __restrict__ freqs, const float* __restrict__ mags,
    const float* __restrict__ W1, const float* __restrict__ b1,
    const float* __restrict__ W2, const float* __restrict__ b2,
    const float* __restrict__ W3, const float* __restrict__ b3,
    float* __restrict__ out, unsigned int* __restrict__ ticket,
    int* __restrict__ cnt)
{
    __shared__ unsigned short sW2T[HID * WS];     // 34816 B
    __shared__ unsigned short sW3T[16 * WS];      //  4352 B (rows 8..15 = 0)
    __shared__ unsigned short sH2[4][16 * WS];    // 17408 B per-wave h2 tile
    __shared__ float sf[PNUM], sm[PNUM];          //  8192 B last-batch f/m
    __shared__ unsigned long long sc[256], sfb[256]; // 4096 B selection keys
    __shared__ int sRed[4];
    __shared__ int sLast;

    const int t = threadIdx.x;
    const int b = blockIdx.x;

    // ---- stage last-batch freqs/mags (float4) ----
    {
        const float4* fb4 = reinterpret_cast<const float4*>(freqs + (size_t)LASTB * PNUM);
        const float4* mb4 = reinterpret_cast<const float4*>(mags  + (size_t)LASTB * PNUM);
        reinterpret_cast<float4*>(sf)[t] = fb4[t];
        reinterpret_cast<float4*>(sm)[t] = mb4[t];
    }

    // ---- stage W2^T (fp32 -> bf16, transposed, 0 measured conflicts) ----
    {
        const float4* __restrict__ w2v = reinterpret_cast<const float4*>(W2);
#pragma unroll
        for (int rep = 0; rep < 16; ++rep) {
            const int e  = rep * 256 + t;        // [0, 4096)
            const int k  = e >> 5;               // row of W2
            const int n0 = (e & 31) * 4;         // col group
            const float4 v = w2v[e];
            sW2T[(n0 + 0) * WS + k] = f2bf(v.x);
            sW2T[(n0 + 1) * WS + k] = f2bf(v.y);
            sW2T[(n0 + 2) * WS + k] = f2bf(v.z);
            sW2T[(n0 + 3) * WS + k] = f2bf(v.w);
        }
    }
    // ---- stage W3^T, rows 8..15 zeroed ----
    {
#pragma unroll
        for (int rep = 0; rep < 5; ++rep) {
            const int idx = rep * 256 + t;
            if (idx < 8 * WS) sW3T[8 * WS + idx] = 0;
        }
#pragma unroll
        for (int rep = 0; rep < 4; ++rep) {
            const int e = rep * 256 + t;         // [0, 1024)
            const int k = e >> 3, o = e & 7;     // W3[k][o]
            sW3T[o * WS + k] = f2bf(W3[e]);
        }
    }
    __syncthreads();

    // =================== harmonic counts: 2 i's per block ===================
    {
        const int i_loc = t >> 7;                // 0..1
        const int jc    = t & 127;               // j-lane within 128
        const int i     = b * 2 + i_loc;
        const float fi  = sf[i];
        float fo[7];
#pragma unroll
        for (int o = 0; o < 7; ++o) fo[o] = __fmul_rn(fi, (float)(o + 2));

        int c = 0;
#pragma unroll
        for (int jj = 0; jj < 8; ++jj) {
            const int j = jj * 128 + jc;
            const float fj = sf[j];
            bool match = false;
#pragma unroll
            for (int o = 0; o < 7; ++o)
                match = match || (fabsf(__fsub_rn(fj, fo[o])) < 2.0f);
            if (match && (sm[j] > 0.0f) && (j != i)) ++c;
        }
#pragma unroll
        for (int off = 32; off > 0; off >>= 1) c += __shfl_down(c, off, 64);
        if ((t & 63) == 0) sRed[t >> 6] = c;
    }
    __syncthreads();
    if ((t & 127) == 0) {
        const int i = b * 2 + (t >> 7);
        __hip_atomic_store(&cnt[i], sRed[(t >> 6)] + sRed[(t >> 6) + 1],
                           __ATOMIC_RELAXED, __HIP_MEMORY_SCOPE_AGENT);
    }

    // =================== MFMA MLP: 128 points/block ===================
    const int w    = t >> 6;
    const int lane = t & 63;
    const int cc   = lane & 15;   // A row / B col / C col within tile
    const int q    = lane >> 4;   // quad
    const int pb   = b * PPB + w * 32;

    // A-frags: h1 for 2 M-tiles x 4 k-chunks, A[m=cc][k=kc*32+q*8+j]
    const int p0 = pb + cc;
    const int p1 = pb + 16 + cc;
    const float f0 = freqs[p0], m0 = mags[p0];
    const float f1 = freqs[p1], m1 = mags[p1];

    short8 af[2][4];
#pragma unroll
    for (int kc = 0; kc < 4; ++kc) {
        const int k0 = kc * 32 + q * 8;
        const float4 wa0 = *(const float4*)&W1[k0];
        const float4 wa1 = *(const float4*)&W1[k0 + 4];
        const float4 wb0 = *(const float4*)&W1[HID + k0];
        const float4 wb1 = *(const float4*)&W1[HID + k0 + 4];
        const float4 bb0 = *(const float4*)&b1[k0];
        const float4 bb1 = *(const float4*)&b1[k0 + 4];
        float h0[8], h1v[8];
        h0[0] = fmaxf(fmaf(f0, wa0.x, fmaf(m0, wb0.x, bb0.x)), 0.0f);
        h0[1] = fmaxf(fmaf(f0, wa0.y, fmaf(m0, wb0.y, bb0.y)), 0.0f);
        h0[2] = fmaxf(fmaf(f0, wa0.z, fmaf(m0, wb0.z, bb0.z)), 0.0f);
        h0[3] = fmaxf(fmaf(f0, wa0.w, fmaf(m0, wb0.w, bb0.w)), 0.0f);
        h0[4] = fmaxf(fmaf(f0, wa1.x, fmaf(m0, wb1.x, bb1.x)), 0.0f);
        h0[5] = fmaxf(fmaf(f0, wa1.y, fmaf(m0, wb1.y, bb1.y)), 0.0f);
        h0[6] = fmaxf(fmaf(f0, wa1.z, fmaf(m0, wb1.z, bb1.z)), 0.0f);
        h0[7] = fmaxf(fmaf(f0, wa1.w, fmaf(m0, wb1.w, bb1.w)), 0.0f);
        h1v[0] = fmaxf(fmaf(f1, wa0.x, fmaf(m1, wb0.x, bb0.x)), 0.0f);
        h1v[1] = fmaxf(fmaf(f1, wa0.y, fmaf(m1, wb0.y, bb0.y)), 0.0f);
        h1v[2] = fmaxf(fmaf(f1, wa0.z, fmaf(m1, wb0.z, bb0.z)), 0.0f);
        h1v[3] = fmaxf(fmaf(f1, wa0.w, fmaf(m1, wb0.w, bb0.w)), 0.0f);
        h1v[4] = fmaxf(fmaf(f1, wa1.x, fmaf(m1, wb1.x, bb1.x)), 0.0f);
        h1v[5] = fmaxf(fmaf(f1, wa1.y, fmaf(m1, wb1.y, bb1.y)), 0.0f);
        h1v[6] = fmaxf(fmaf(f1, wa1.z, fmaf(m1, wb1.z, bb1.z)), 0.0f);
        h1v[7] = fmaxf(fmaf(f1, wa1.w, fmaf(m1, wb1.w, bb1.w)), 0.0f);
        union { short8 s; unsigned u[4]; } u0, u1;
        u0.u[0] = pk2(h0[0], h0[1]);  u0.u[1] = pk2(h0[2], h0[3]);
        u0.u[2] = pk2(h0[4], h0[5]);  u0.u[3] = pk2(h0[6], h0[7]);
        u1.u[0] = pk2(h1v[0], h1v[1]); u1.u[1] = pk2(h1v[2], h1v[3]);
        u1.u[2] = pk2(h1v[4], h1v[5]); u1.u[3] = pk2(h1v[6], h1v[7]);
        af[0][kc] = u0.s;
        af[1][kc] = u1.s;
    }

    float b2v[8];
#pragma unroll
    for (int nt = 0; nt < 8; ++nt) b2v[nt] = b2[nt * 16 + cc];
    const float b3v = (cc < 8) ? b3[cc] : 0.0f;

    // W3 B-frags: B[k=kc*32+q*8+j][n=cc]
    short8 bw3[4];
#pragma unroll
    for (int kc = 0; kc < 4; ++kc)
        bw3[kc] = *(const short8*)&sW3T[cc * WS + kc * 32 + q * 8];

    // ---- layer 2: 64 MFMAs ----
    f32x4 acc[2][8];
#pragma unroll
    for (int mt = 0; mt < 2; ++mt)
#pragma unroll
        for (int nt = 0; nt < 8; ++nt) {
            f32x4 z = {0.0f, 0.0f, 0.0f, 0.0f};
            acc[mt][nt] = z;
        }
#pragma unroll
    for (int nt = 0; nt < 8; ++nt)
#pragma unroll
        for (int kc = 0; kc < 4; ++kc) {
            const short8 bf =
                *(const short8*)&sW2T[(nt * 16 + cc) * WS + kc * 32 + q * 8];
            acc[0][nt] = __builtin_amdgcn_mfma_f32_16x16x32_bf16(
                af[0][kc], bf, acc[0][nt], 0, 0, 0);
            acc[1][nt] = __builtin_amdgcn_mfma_f32_16x16x32_bf16(
                af[1][kc], bf, acc[1][nt], 0, 0, 0);
        }

    // ---- layer 3 + store, per M-tile (per-wave LDS C->A relayout) ----
    unsigned short* __restrict__ myH2 = sH2[w];
#pragma unroll
    for (int mt = 0; mt < 2; ++mt) {
#pragma unroll
        for (int nt = 0; nt < 8; ++nt) {
            const f32x4 v = acc[mt][nt];
#pragma unroll
            for (int r = 0; r < 4; ++r)
                myH2[(q * 4 + r) * WS + nt * 16 + cc] =
                    f2bf(fmaxf(v[r] + b2v[nt], 0.0f));
        }
        f32x4 oa = {0.0f, 0.0f, 0.0f, 0.0f};
#pragma unroll
        for (int kc = 0; kc < 4; ++kc) {
            const short8 a3 = *(const short8*)&myH2[cc * WS + kc * 32 + q * 8];
            oa = __builtin_amdgcn_mfma_f32_16x16x32_bf16(a3, bw3[kc], oa, 0, 0, 0);
        }
        if (cc < 8) {
            const int pg = pb + mt * 16 + q * 4;
#pragma unroll
            for (int r = 0; r < 4; ++r)
                out[(size_t)(pg + r) * 8 + cc] = oa[r] + b3v;
        }
    }

    // =================== ticket + selection (last block) ===================
    __syncthreads();   // order both cnt stores before the ticket RMW
    if (t == 0) {
        __threadfence();
        const unsigned int old = __hip_atomic_fetch_add(
            ticket, 1u, __ATOMIC_ACQ_REL, __HIP_MEMORY_SCOPE_AGENT);
        sLast = (old == NBLK - 1) ? 1 : 0;
    }
    __syncthreads();

    if (sLast) {
        __threadfence();
        unsigned long long ck = 0ull, fk = 0ull;
#pragma unroll
        for (int r = 0; r < 4; ++r) {
            const int i2 = t + 256 * r;
            const float mi = sm[i2];
            const int h = __hip_atomic_load(&cnt[i2], __ATOMIC_RELAXED,
                                            __HIP_MEMORY_SCOPE_AGENT);
            const unsigned mbits = __float_as_uint(mi);
            if (mi > 0.0f && h > 0) {
                const unsigned long long k =
                    ((unsigned long long)h << 42) |
                    ((unsigned long long)mbits << 10) |
                    (unsigned long long)(1023 - i2);
                ck = umax64(ck, k);
            }
            const unsigned mo =
                (mbits & 0x80000000u) ? ~mbits : (mbits | 0x80000000u);
            const unsigned long long k2 =
                ((unsigned long long)mo << 10) |
                (unsigned long long)(1023 - i2);
            fk = umax64(fk, k2);
        }
        sc[t] = ck;
        sfb[t] = fk;
        __syncthreads();
        for (int s = 128; s > 0; s >>= 1) {
            if (t < s) {
                sc[t]  = umax64(sc[t],  sc[t + s]);
                sfb[t] = umax64(sfb[t], sfb[t + s]);
            }
            __syncthreads();
        }
        if (t == 0) {
            const unsigned long long k = sc[0] ? sc[0] : sfb[0];
            const int idx = 1023 - (int)(k & 1023ull);
            out[(size_t)BP * 8] = sf[idx];
        }
    }
}

// ---------------------------------------------------------------------------
extern "C" void kernel_launch(void* const* d_in, const int* in_sizes, int n_in,
                              void* d_out, int out_size, void* d_ws, size_t ws_size,
                              hipStream_t stream) {
    const float* freqs = (const float*)d_in[0];
    const float* mags  = (const float*)d_in[1];
    const float* W1    = (const float*)d_in[2];
    const float* b1    = (const float*)d_in[3];
    const float* W2    = (const float*)d_in[4];
    const float* b2    = (const float*)d_in[5];
    const float* W3    = (const float*)d_in[6];
    const float* b3    = (const float*)d_in[7];
    float* out = (float*)d_out;

    unsigned int* ticket = (unsigned int*)d_ws;
    int* cnt = (int*)((char*)d_ws + 256);

    hipMemsetAsync(d_ws, 0, 4, stream);   // zero the ticket (d_ws is poisoned)
    fused<<<NBLK, 256, 0, stream>>>(freqs, mags, W1, b1, W2, b2, W3, b3,
                                    out, ticket, cnt);
}

// Round 6
// 80.835 us; speedup vs baseline: 1.3884x; 1.3884x over previous
//
#include <hip/hip_runtime.h>
#include <hip/hip_bf16.h>

#define HID   128
#define PNUM  1024
#define LASTB 63
#define BP    (64 * PNUM)   // 65536 points
#define NBLK  512           // all blocks: harm(2 i's) + MLP(128 pts)
#define PPB   128           // points per block
#define H2S   132           // sH2 row stride in floats (16B-aligned, 2-way free)

typedef __attribute__((ext_vector_type(8))) short short8;   // 8 bf16 = 4 VGPRs
typedef __attribute__((ext_vector_type(4))) float f32x4;    // MFMA C/D

__device__ __forceinline__ unsigned short f2bf(float x) {
    unsigned u = __float_as_uint(x);
    return (unsigned short)((u + 0x7FFFu + ((u >> 16) & 1u)) >> 16);
}
__device__ __forceinline__ unsigned pk2(float a, float b) {
    __hip_bfloat162 h = __float22bfloat162_rn(make_float2(a, b));
    union { __hip_bfloat162 h2; unsigned u; } c;
    c.h2 = h;
    return c.u;
}
__device__ __forceinline__ unsigned long long umax64(unsigned long long a,
                                                     unsigned long long b) {
    return a > b ? a : b;
}

// ---------------------------------------------------------------------------
// Kernel A: 512 blocks x 256 threads. No fences, no ticket.
//  - stage sf/sm + W2^T/W3^T (bf16, XOR chunk-swizzled: slot = c ^ (n&15))
//  - harm counts for 2 i's per block -> per-block candidate-key atomicMax
//    into ws (8 contention-split words); block 0 computes fallback key.
//  - MFMA MLP for 128 points (A-frag h1 in regs; B-frag W2T from LDS;
//    layer-3 via per-wave fp32 LDS round-trip, stride 132 = conflict-free).
// Kernel B (1 block): reduce the 9 key words, write the fundamental freq.
// ---------------------------------------------------------------------------
__global__ __launch_bounds__(256) void fusedA(
    const float* __restrict__ freqs, const float* __restrict__ mags,
    const float* __restrict__ W1, const float* __restrict__ b1,
    const float* __restrict__ W2, const float* __restrict__ b2,
    const float* __restrict__ W3, const float* __restrict__ b3,
    float* __restrict__ out, unsigned long long* __restrict__ ck8,
    unsigned long long* __restrict__ fkW)
{
    __shared__ unsigned short sW2T[HID * HID];    // 32768 B, swizzled chunks
    __shared__ unsigned short sW3T[16 * HID];     //  4096 B, rows 8..15 = 0
    __shared__ float sH2[4][16 * H2S];            // 33792 B per-wave h2 (fp32)
    __shared__ float sf[PNUM], sm[PNUM];          //  8192 B last-batch f/m
    __shared__ unsigned long long sfb[256];       //  2048 B block-0 fallback
    __shared__ int sRed[4];

    const int t = threadIdx.x;
    const int b = blockIdx.x;

    // ---- stage last-batch freqs/mags (float4) ----
    {
        const float4* fb4 = reinterpret_cast<const float4*>(freqs + (size_t)LASTB * PNUM);
        const float4* mb4 = reinterpret_cast<const float4*>(mags  + (size_t)LASTB * PNUM);
        reinterpret_cast<float4*>(sf)[t] = fb4[t];
        reinterpret_cast<float4*>(sm)[t] = mb4[t];
    }

    // ---- stage W2^T bf16, chunk-swizzled, ds_write_b128 only ----
    // thread: n = t&127, half = t>>7; rep r -> chunk c = r*2+half (k = c*8..+7)
    {
        const int n    = t & 127;
        const int half = t >> 7;
#pragma unroll
        for (int r = 0; r < 8; ++r) {
            const int c  = r * 2 + half;
            const int k0 = c * 8;
            float v[8];
#pragma unroll
            for (int j = 0; j < 8; ++j) v[j] = W2[(k0 + j) * HID + n];  // coalesced in n
            union { short8 s; unsigned u[4]; } pk;
            pk.u[0] = pk2(v[0], v[1]); pk.u[1] = pk2(v[2], v[3]);
            pk.u[2] = pk2(v[4], v[5]); pk.u[3] = pk2(v[6], v[7]);
            *(short8*)&sW2T[n * HID + (c ^ (n & 15)) * 8] = pk.s;
        }
    }
    // ---- stage W3^T bf16 (rows 8..15 zero), same swizzle ----
    {
        const int o = t >> 4;   // 0..15
        const int c = t & 15;   // chunk
        union { short8 s; unsigned u[4]; } pk;
        if (o < 8) {
            float v[8];
#pragma unroll
            for (int j = 0; j < 8; ++j) v[j] = W3[(c * 8 + j) * 8 + o];
            pk.u[0] = pk2(v[0], v[1]); pk.u[1] = pk2(v[2], v[3]);
            pk.u[2] = pk2(v[4], v[5]); pk.u[3] = pk2(v[6], v[7]);
        } else {
            pk.u[0] = pk.u[1] = pk.u[2] = pk.u[3] = 0u;
        }
        *(short8*)&sW3T[o * HID + (c ^ (o & 15)) * 8] = pk.s;
    }
    __syncthreads();

    // =================== harmonic counts: 2 i's per block ===================
    {
        const int i_loc = t >> 7;                // 0..1
        const int jc    = t & 127;
        const int i     = b * 2 + i_loc;
        const float fi  = sf[i];
        float fo[7];
#pragma unroll
        for (int o = 0; o < 7; ++o) fo[o] = __fmul_rn(fi, (float)(o + 2));

        int c = 0;
#pragma unroll
        for (int jj = 0; jj < 8; ++jj) {
            const int j = jj * 128 + jc;         // lane-consecutive: conflict-free
            const float fj = sf[j];
            bool match = false;
#pragma unroll
            for (int o = 0; o < 7; ++o)
                match = match || (fabsf(__fsub_rn(fj, fo[o])) < 2.0f);
            if (match && (sm[j] > 0.0f) && (j != i)) ++c;
        }
#pragma unroll
        for (int off = 32; off > 0; off >>= 1) c += __shfl_down(c, off, 64);
        if ((t & 63) == 0) sRed[t >> 6] = c;
    }
    __syncthreads();

    // ---- per-block candidate keys -> contention-split atomicMax ----
    if ((t & 127) == 0) {
        const int i = b * 2 + (t >> 7);
        const int h = sRed[(t >> 6)] + sRed[(t >> 6) + 1];
        const float mi = sm[i];
        if (mi > 0.0f && h > 0) {
            const unsigned long long key =
                ((unsigned long long)h << 42) |
                ((unsigned long long)__float_as_uint(mi) << 10) |
                (unsigned long long)(1023 - i);
            __hip_atomic_fetch_max(&ck8[b & 7], key, __ATOMIC_RELAXED,
                                   __HIP_MEMORY_SCOPE_AGENT);
        }
    }

    // ---- block 0: fallback key (argmax of mags, ties -> smallest i) ----
    if (b == 0) {
        unsigned long long fk = 0ull;
#pragma unroll
        for (int r = 0; r < 4; ++r) {
            const int i2 = t + 256 * r;
            const unsigned mb = __float_as_uint(sm[i2]);
            const unsigned mo = (mb & 0x80000000u) ? ~mb : (mb | 0x80000000u);
            fk = umax64(fk, ((unsigned long long)mo << 10) |
                            (unsigned long long)(1023 - i2));
        }
        sfb[t] = fk;
        __syncthreads();
        for (int s = 128; s > 0; s >>= 1) {
            if (t < s) sfb[t] = umax64(sfb[t], sfb[t + s]);
            __syncthreads();
        }
        if (t == 0)
            __hip_atomic_fetch_max(fkW, sfb[0], __ATOMIC_RELAXED,
                                   __HIP_MEMORY_SCOPE_AGENT);
    }

    // =================== MFMA MLP: 128 points/block ===================
    const int w    = t >> 6;
    const int lane = t & 63;
    const int cc   = lane & 15;   // A row / B col / C col within tile
    const int q    = lane >> 4;   // quad
    const int pb   = b * PPB + w * 32;

    const int p0 = pb + cc;
    const int p1 = pb + 16 + cc;
    const float f0 = freqs[p0], m0 = mags[p0];
    const float f1 = freqs[p1], m1 = mags[p1];

    // A-frags: h1, A[m=cc][k=kc*32+q*8+j]
    short8 af[2][4];
#pragma unroll
    for (int kc = 0; kc < 4; ++kc) {
        const int k0 = kc * 32 + q * 8;
        const float4 wa0 = *(const float4*)&W1[k0];
        const float4 wa1 = *(const float4*)&W1[k0 + 4];
        const float4 wb0 = *(const float4*)&W1[HID + k0];
        const float4 wb1 = *(const float4*)&W1[HID + k0 + 4];
        const float4 bb0 = *(const float4*)&b1[k0];
        const float4 bb1 = *(const float4*)&b1[k0 + 4];
        float h0[8], h1v[8];
        h0[0] = fmaxf(fmaf(f0, wa0.x, fmaf(m0, wb0.x, bb0.x)), 0.0f);
        h0[1] = fmaxf(fmaf(f0, wa0.y, fmaf(m0, wb0.y, bb0.y)), 0.0f);
        h0[2] = fmaxf(fmaf(f0, wa0.z, fmaf(m0, wb0.z, bb0.z)), 0.0f);
        h0[3] = fmaxf(fmaf(f0, wa0.w, fmaf(m0, wb0.w, bb0.w)), 0.0f);
        h0[4] = fmaxf(fmaf(f0, wa1.x, fmaf(m0, wb1.x, bb1.x)), 0.0f);
        h0[5] = fmaxf(fmaf(f0, wa1.y, fmaf(m0, wb1.y, bb1.y)), 0.0f);
        h0[6] = fmaxf(fmaf(f0, wa1.z, fmaf(m0, wb1.z, bb1.z)), 0.0f);
        h0[7] = fmaxf(fmaf(f0, wa1.w, fmaf(m0, wb1.w, bb1.w)), 0.0f);
        h1v[0] = fmaxf(fmaf(f1, wa0.x, fmaf(m1, wb0.x, bb0.x)), 0.0f);
        h1v[1] = fmaxf(fmaf(f1, wa0.y, fmaf(m1, wb0.y, bb0.y)), 0.0f);
        h1v[2] = fmaxf(fmaf(f1, wa0.z, fmaf(m1, wb0.z, bb0.z)), 0.0f);
        h1v[3] = fmaxf(fmaf(f1, wa0.w, fmaf(m1, wb0.w, bb0.w)), 0.0f);
        h1v[4] = fmaxf(fmaf(f1, wa1.x, fmaf(m1, wb1.x, bb1.x)), 0.0f);
        h1v[5] = fmaxf(fmaf(f1, wa1.y, fmaf(m1, wb1.y, bb1.y)), 0.0f);
        h1v[6] = fmaxf(fmaf(f1, wa1.z, fmaf(m1, wb1.z, bb1.z)), 0.0f);
        h1v[7] = fmaxf(fmaf(f1, wa1.w, fmaf(m1, wb1.w, bb1.w)), 0.0f);
        union { short8 s; unsigned u[4]; } u0, u1;
        u0.u[0] = pk2(h0[0], h0[1]);   u0.u[1] = pk2(h0[2], h0[3]);
        u0.u[2] = pk2(h0[4], h0[5]);   u0.u[3] = pk2(h0[6], h0[7]);
        u1.u[0] = pk2(h1v[0], h1v[1]); u1.u[1] = pk2(h1v[2], h1v[3]);
        u1.u[2] = pk2(h1v[4], h1v[5]); u1.u[3] = pk2(h1v[6], h1v[7]);
        af[0][kc] = u0.s;
        af[1][kc] = u1.s;
    }

    float b2v[8];
#pragma unroll
    for (int nt = 0; nt < 8; ++nt) b2v[nt] = b2[nt * 16 + cc];
    const float b3v = (cc < 8) ? b3[cc] : 0.0f;

    // W3 B-frags: row cc, chunk (kc*4+q) ^ cc
    short8 bw3[4];
#pragma unroll
    for (int kc = 0; kc < 4; ++kc)
        bw3[kc] = *(const short8*)&sW3T[cc * HID + ((kc * 4 + q) ^ cc) * 8];

    // ---- layer 2: 64 MFMAs ----
    f32x4 acc[2][8];
#pragma unroll
    for (int mt = 0; mt < 2; ++mt)
#pragma unroll
        for (int nt = 0; nt < 8; ++nt) {
            f32x4 z = {0.0f, 0.0f, 0.0f, 0.0f};
            acc[mt][nt] = z;
        }
#pragma unroll
    for (int nt = 0; nt < 8; ++nt)
#pragma unroll
        for (int kc = 0; kc < 4; ++kc) {
            const short8 bf = *(const short8*)
                &sW2T[(nt * 16 + cc) * HID + ((kc * 4 + q) ^ cc) * 8];
            acc[0][nt] = __builtin_amdgcn_mfma_f32_16x16x32_bf16(
                af[0][kc], bf, acc[0][nt], 0, 0, 0);
            acc[1][nt] = __builtin_amdgcn_mfma_f32_16x16x32_bf16(
                af[1][kc], bf, acc[1][nt], 0, 0, 0);
        }

    // ---- layer 3 + store, per M-tile (per-wave fp32 LDS C->A relayout) ----
    float* __restrict__ myH2 = sH2[w];
#pragma unroll
    for (int mt = 0; mt < 2; ++mt) {
#pragma unroll
        for (int nt = 0; nt < 8; ++nt) {
            const f32x4 v = acc[mt][nt];
#pragma unroll
            for (int r = 0; r < 4; ++r)
                myH2[(q * 4 + r) * H2S + nt * 16 + cc] =
                    fmaxf(v[r] + b2v[nt], 0.0f);       // b32, 2-way = free
        }
        f32x4 oa = {0.0f, 0.0f, 0.0f, 0.0f};
#pragma unroll
        for (int kc = 0; kc < 4; ++kc) {
            const float4 x0 = *(const float4*)&myH2[cc * H2S + kc * 32 + q * 8];
            const float4 x1 = *(const float4*)&myH2[cc * H2S + kc * 32 + q * 8 + 4];
            union { short8 s; unsigned u[4]; } pk;
            pk.u[0] = pk2(x0.x, x0.y); pk.u[1] = pk2(x0.z, x0.w);
            pk.u[2] = pk2(x1.x, x1.y); pk.u[3] = pk2(x1.z, x1.w);
            oa = __builtin_amdgcn_mfma_f32_16x16x32_bf16(pk.s, bw3[kc], oa, 0, 0, 0);
        }
        if (cc < 8) {
            const int pg = pb + mt * 16 + q * 4;
#pragma unroll
            for (int r = 0; r < 4; ++r)
                out[(size_t)(pg + r) * 8 + cc] = oa[r] + b3v;
        }
    }
}

// ---------------------------------------------------------------------------
// Kernel B: final pick. Stream ordering after A gives coherence — no fences.
// ---------------------------------------------------------------------------
__global__ __launch_bounds__(64) void finalize(
    const float* __restrict__ freqs, const unsigned long long* __restrict__ ck8,
    const unsigned long long* __restrict__ fkW, float* __restrict__ outF)
{
    if (threadIdx.x == 0) {
        unsigned long long k = 0ull;
#pragma unroll
        for (int i = 0; i < 8; ++i) k = umax64(k, ck8[i]);
        if (k == 0ull) k = *fkW;
        const int idx = 1023 - (int)(k & 1023ull);
        outF[0] = freqs[(size_t)LASTB * PNUM + idx];
    }
}

// ---------------------------------------------------------------------------
extern "C" void kernel_launch(void* const* d_in, const int* in_sizes, int n_in,
                              void* d_out, int out_size, void* d_ws, size_t ws_size,
                              hipStream_t stream) {
    const float* freqs = (const float*)d_in[0];
    const float* mags  = (const float*)d_in[1];
    const float* W1    = (const float*)d_in[2];
    const float* b1    = (const float*)d_in[3];
    const float* W2    = (const float*)d_in[4];
    const float* b2    = (const float*)d_in[5];
    const float* W3    = (const float*)d_in[6];
    const float* b3    = (const float*)d_in[7];
    float* out = (float*)d_out;

    unsigned long long* ck8 = (unsigned long long*)d_ws;             // 8 words
    unsigned long long* fkW = (unsigned long long*)((char*)d_ws + 64);

    hipMemsetAsync(d_ws, 0, 128, stream);   // zero key words (ws is poisoned)
    fusedA<<<NBLK, 256, 0, stream>>>(freqs, mags, W1, b1, W2, b2, W3, b3,
                                     out, ck8, fkW);
    finalize<<<1, 64, 0, stream>>>(freqs, ck8, fkW, out + (size_t)BP * 8);
}

// Round 7
// 80.085 us; speedup vs baseline: 1.4014x; 1.0094x over previous
//
#include <hip/hip_runtime.h>
#include <hip/hip_bf16.h>

#define HID   128
#define PNUM  1024
#define LASTB 63
#define BP    (64 * PNUM)   // 65536 points
#define NBLK  512           // all blocks: harm(2 i's) + MLP(128 pts)
#define PPB   128           // points per block
#define H2S   132           // sH2 row stride in floats (16B-aligned, 2-way free)

typedef __attribute__((ext_vector_type(8))) short short8;   // 8 bf16 = 4 VGPRs
typedef __attribute__((ext_vector_type(4))) float f32x4;    // MFMA C/D

__device__ __forceinline__ unsigned pk2(float a, float b) {
    __hip_bfloat162 h = __float22bfloat162_rn(make_float2(a, b));
    union { __hip_bfloat162 h2; unsigned u; } c;
    c.h2 = h;
    return c.u;
}
__device__ __forceinline__ unsigned long long umax64(unsigned long long a,
                                                     unsigned long long b) {
    return a > b ? a : b;
}

// ---------------------------------------------------------------------------
// Kernel A: 512 blocks x 256 threads. No fences, no ticket, NO ws memset:
// every block unconditionally stores its best candidate key to ckArr[b]
// (0 if none), so the poisoned ws is fully overwritten each launch. Block 0
// also stores the fallback (argmax-mag) key. Kernel-boundary ordering makes
// finalize coherent.
//  - W2^T/W3^T staged bf16 in LDS, XOR chunk-swizzle (slot = c ^ (n&15)):
//    ds_write_b128 / ds_read_b128 both conflict-free (R6: conflicts 4.3M->0).
//  - MLP: per wave 32 points, mfma_f32_16x16x32_bf16; layer-3 via per-wave
//    fp32 LDS round-trip (stride 132 floats = exact 2-way = free).
// ---------------------------------------------------------------------------
__global__ __launch_bounds__(256) void fusedA(
    const float* __restrict__ freqs, const float* __restrict__ mags,
    const float* __restrict__ W1, const float* __restrict__ b1,
    const float* __restrict__ W2, const float* __restrict__ b2,
    const float* __restrict__ W3, const float* __restrict__ b3,
    float* __restrict__ out, unsigned long long* __restrict__ ckArr,
    unsigned long long* __restrict__ fkW)
{
    __shared__ unsigned short sW2T[HID * HID];    // 32768 B, swizzled chunks
    __shared__ unsigned short sW3T[16 * HID];     //  4096 B, rows 8..15 = 0
    __shared__ float sH2[4][16 * H2S];            // 33792 B per-wave h2 (fp32)
    __shared__ float sf[PNUM], sm[PNUM];          //  8192 B last-batch f/m
    __shared__ unsigned long long sfb[256];       //  2048 B block-0 fallback
    __shared__ unsigned long long sKey[2];
    __shared__ int sRed[4];

    const int t = threadIdx.x;
    const int b = blockIdx.x;

    // ---- stage last-batch freqs/mags (float4) ----
    {
        const float4* fb4 = reinterpret_cast<const float4*>(freqs + (size_t)LASTB * PNUM);
        const float4* mb4 = reinterpret_cast<const float4*>(mags  + (size_t)LASTB * PNUM);
        reinterpret_cast<float4*>(sf)[t] = fb4[t];
        reinterpret_cast<float4*>(sm)[t] = mb4[t];
    }

    // ---- stage W2^T bf16, chunk-swizzled, ds_write_b128 only ----
    {
        const int n    = t & 127;
        const int half = t >> 7;
#pragma unroll
        for (int r = 0; r < 8; ++r) {
            const int c  = r * 2 + half;
            const int k0 = c * 8;
            float v[8];
#pragma unroll
            for (int j = 0; j < 8; ++j) v[j] = W2[(k0 + j) * HID + n];  // coalesced in n
            union { short8 s; unsigned u[4]; } pk;
            pk.u[0] = pk2(v[0], v[1]); pk.u[1] = pk2(v[2], v[3]);
            pk.u[2] = pk2(v[4], v[5]); pk.u[3] = pk2(v[6], v[7]);
            *(short8*)&sW2T[n * HID + (c ^ (n & 15)) * 8] = pk.s;
        }
    }
    // ---- stage W3^T bf16 (rows 8..15 zero), same swizzle ----
    {
        const int o = t >> 4;   // 0..15
        const int c = t & 15;   // chunk
        union { short8 s; unsigned u[4]; } pk;
        if (o < 8) {
            float v[8];
#pragma unroll
            for (int j = 0; j < 8; ++j) v[j] = W3[(c * 8 + j) * 8 + o];
            pk.u[0] = pk2(v[0], v[1]); pk.u[1] = pk2(v[2], v[3]);
            pk.u[2] = pk2(v[4], v[5]); pk.u[3] = pk2(v[6], v[7]);
        } else {
            pk.u[0] = pk.u[1] = pk.u[2] = pk.u[3] = 0u;
        }
        *(short8*)&sW3T[o * HID + (c ^ (o & 15)) * 8] = pk.s;
    }
    __syncthreads();

    // =================== harmonic counts: 2 i's per block ===================
    {
        const int i_loc = t >> 7;                // 0..1
        const int jc    = t & 127;
        const int i     = b * 2 + i_loc;
        const float fi  = sf[i];
        float fo[7];
#pragma unroll
        for (int o = 0; o < 7; ++o) fo[o] = __fmul_rn(fi, (float)(o + 2));

        int c = 0;
#pragma unroll
        for (int jj = 0; jj < 8; ++jj) {
            const int j = jj * 128 + jc;         // lane-consecutive: conflict-free
            const float fj = sf[j];
            bool match = false;
#pragma unroll
            for (int o = 0; o < 7; ++o)
                match = match || (fabsf(__fsub_rn(fj, fo[o])) < 2.0f);
            if (match && (sm[j] > 0.0f) && (j != i)) ++c;
        }
#pragma unroll
        for (int off = 32; off > 0; off >>= 1) c += __shfl_down(c, off, 64);
        if ((t & 63) == 0) sRed[t >> 6] = c;
    }
    __syncthreads();

    // ---- per-block best candidate key -> ckArr[b] (unconditional store) ----
    if ((t & 127) == 0) {
        const int i = b * 2 + (t >> 7);
        const int h = sRed[(t >> 6)] + sRed[(t >> 6) + 1];
        const float mi = sm[i];
        unsigned long long key = 0ull;
        if (mi > 0.0f && h > 0)
            key = ((unsigned long long)h << 42) |
                  ((unsigned long long)__float_as_uint(mi) << 10) |
                  (unsigned long long)(1023 - i);
        sKey[t >> 7] = key;
    }
    __syncthreads();
    if (t == 0) ckArr[b] = umax64(sKey[0], sKey[1]);

    // ---- block 0: fallback key (argmax of mags, ties -> smallest i) ----
    if (b == 0) {
        unsigned long long fk = 0ull;
#pragma unroll
        for (int r = 0; r < 4; ++r) {
            const int i2 = t + 256 * r;
            const unsigned mb = __float_as_uint(sm[i2]);
            const unsigned mo = (mb & 0x80000000u) ? ~mb : (mb | 0x80000000u);
            fk = umax64(fk, ((unsigned long long)mo << 10) |
                            (unsigned long long)(1023 - i2));
        }
        sfb[t] = fk;
        __syncthreads();
        for (int s = 128; s > 0; s >>= 1) {
            if (t < s) sfb[t] = umax64(sfb[t], sfb[t + s]);
            __syncthreads();
        }
        if (t == 0) *fkW = sfb[0];
    }

    // =================== MFMA MLP: 128 points/block ===================
    const int w    = t >> 6;
    const int lane = t & 63;
    const int cc   = lane & 15;   // A row / B col / C col within tile
    const int q    = lane >> 4;   // quad
    const int pb   = b * PPB + w * 32;

    const int p0 = pb + cc;
    const int p1 = pb + 16 + cc;
    const float f0 = freqs[p0], m0 = mags[p0];
    const float f1 = freqs[p1], m1 = mags[p1];

    // A-frags: h1, A[m=cc][k=kc*32+q*8+j]
    short8 af[2][4];
#pragma unroll
    for (int kc = 0; kc < 4; ++kc) {
        const int k0 = kc * 32 + q * 8;
        const float4 wa0 = *(const float4*)&W1[k0];
        const float4 wa1 = *(const float4*)&W1[k0 + 4];
        const float4 wb0 = *(const float4*)&W1[HID + k0];
        const float4 wb1 = *(const float4*)&W1[HID + k0 + 4];
        const float4 bb0 = *(const float4*)&b1[k0];
        const float4 bb1 = *(const float4*)&b1[k0 + 4];
        float h0[8], h1v[8];
        h0[0] = fmaxf(fmaf(f0, wa0.x, fmaf(m0, wb0.x, bb0.x)), 0.0f);
        h0[1] = fmaxf(fmaf(f0, wa0.y, fmaf(m0, wb0.y, bb0.y)), 0.0f);
        h0[2] = fmaxf(fmaf(f0, wa0.z, fmaf(m0, wb0.z, bb0.z)), 0.0f);
        h0[3] = fmaxf(fmaf(f0, wa0.w, fmaf(m0, wb0.w, bb0.w)), 0.0f);
        h0[4] = fmaxf(fmaf(f0, wa1.x, fmaf(m0, wb1.x, bb1.x)), 0.0f);
        h0[5] = fmaxf(fmaf(f0, wa1.y, fmaf(m0, wb1.y, bb1.y)), 0.0f);
        h0[6] = fmaxf(fmaf(f0, wa1.z, fmaf(m0, wb1.z, bb1.z)), 0.0f);
        h0[7] = fmaxf(fmaf(f0, wa1.w, fmaf(m0, wb1.w, bb1.w)), 0.0f);
        h1v[0] = fmaxf(fmaf(f1, wa0.x, fmaf(m1, wb0.x, bb0.x)), 0.0f);
        h1v[1] = fmaxf(fmaf(f1, wa0.y, fmaf(m1, wb0.y, bb0.y)), 0.0f);
        h1v[2] = fmaxf(fmaf(f1, wa0.z, fmaf(m1, wb0.z, bb0.z)), 0.0f);
        h1v[3] = fmaxf(fmaf(f1, wa0.w, fmaf(m1, wb0.w, bb0.w)), 0.0f);
        h1v[4] = fmaxf(fmaf(f1, wa1.x, fmaf(m1, wb1.x, bb1.x)), 0.0f);
        h1v[5] = fmaxf(fmaf(f1, wa1.y, fmaf(m1, wb1.y, bb1.y)), 0.0f);
        h1v[6] = fmaxf(fmaf(f1, wa1.z, fmaf(m1, wb1.z, bb1.z)), 0.0f);
        h1v[7] = fmaxf(fmaf(f1, wa1.w, fmaf(m1, wb1.w, bb1.w)), 0.0f);
        union { short8 s; unsigned u[4]; } u0, u1;
        u0.u[0] = pk2(h0[0], h0[1]);   u0.u[1] = pk2(h0[2], h0[3]);
        u0.u[2] = pk2(h0[4], h0[5]);   u0.u[3] = pk2(h0[6], h0[7]);
        u1.u[0] = pk2(h1v[0], h1v[1]); u1.u[1] = pk2(h1v[2], h1v[3]);
        u1.u[2] = pk2(h1v[4], h1v[5]); u1.u[3] = pk2(h1v[6], h1v[7]);
        af[0][kc] = u0.s;
        af[1][kc] = u1.s;
    }

    float b2v[8];
#pragma unroll
    for (int nt = 0; nt < 8; ++nt) b2v[nt] = b2[nt * 16 + cc];
    const float b3v = (cc < 8) ? b3[cc] : 0.0f;

    // W3 B-frags: row cc, chunk (kc*4+q) ^ cc
    short8 bw3[4];
#pragma unroll
    for (int kc = 0; kc < 4; ++kc)
        bw3[kc] = *(const short8*)&sW3T[cc * HID + ((kc * 4 + q) ^ cc) * 8];

    // ---- layer 2: 64 MFMAs ----
    f32x4 acc[2][8];
#pragma unroll
    for (int mt = 0; mt < 2; ++mt)
#pragma unroll
        for (int nt = 0; nt < 8; ++nt) {
            f32x4 z = {0.0f, 0.0f, 0.0f, 0.0f};
            acc[mt][nt] = z;
        }
#pragma unroll
    for (int nt = 0; nt < 8; ++nt)
#pragma unroll
        for (int kc = 0; kc < 4; ++kc) {
            const short8 bf = *(const short8*)
                &sW2T[(nt * 16 + cc) * HID + ((kc * 4 + q) ^ cc) * 8];
            acc[0][nt] = __builtin_amdgcn_mfma_f32_16x16x32_bf16(
                af[0][kc], bf, acc[0][nt], 0, 0, 0);
            acc[1][nt] = __builtin_amdgcn_mfma_f32_16x16x32_bf16(
                af[1][kc], bf, acc[1][nt], 0, 0, 0);
        }

    // ---- layer 3 + store, per M-tile (per-wave fp32 LDS C->A relayout) ----
    float* __restrict__ myH2 = sH2[w];
#pragma unroll
    for (int mt = 0; mt < 2; ++mt) {
#pragma unroll
        for (int nt = 0; nt < 8; ++nt) {
            const f32x4 v = acc[mt][nt];
#pragma unroll
            for (int r = 0; r < 4; ++r)
                myH2[(q * 4 + r) * H2S + nt * 16 + cc] =
                    fmaxf(v[r] + b2v[nt], 0.0f);       // b32, 2-way = free
        }
        f32x4 oa = {0.0f, 0.0f, 0.0f, 0.0f};
#pragma unroll
        for (int kc = 0; kc < 4; ++kc) {
            const float4 x0 = *(const float4*)&myH2[cc * H2S + kc * 32 + q * 8];
            const float4 x1 = *(const float4*)&myH2[cc * H2S + kc * 32 + q * 8 + 4];
            union { short8 s; unsigned u[4]; } pk;
            pk.u[0] = pk2(x0.x, x0.y); pk.u[1] = pk2(x0.z, x0.w);
            pk.u[2] = pk2(x1.x, x1.y); pk.u[3] = pk2(x1.z, x1.w);
            oa = __builtin_amdgcn_mfma_f32_16x16x32_bf16(pk.s, bw3[kc], oa, 0, 0, 0);
        }
        if (cc < 8) {
            const int pg = pb + mt * 16 + q * 4;
#pragma unroll
            for (int r = 0; r < 4; ++r)
                out[(size_t)(pg + r) * 8 + cc] = oa[r] + b3v;
        }
    }
}

// ---------------------------------------------------------------------------
// Kernel B: final pick over 512 per-block keys + fallback. Stream ordering
// after A gives coherence — no fences.
// ---------------------------------------------------------------------------
__global__ __launch_bounds__(256) void finalize(
    const float* __restrict__ freqs, const unsigned long long* __restrict__ ckArr,
    const unsigned long long* __restrict__ fkW, float* __restrict__ outF)
{
    __shared__ unsigned long long sK[256];
    const int t = threadIdx.x;
    sK[t] = umax64(ckArr[t], ckArr[t + 256]);
    __syncthreads();
    for (int s = 128; s > 0; s >>= 1) {
        if (t < s) sK[t] = umax64(sK[t], sK[t + s]);
        __syncthreads();
    }
    if (t == 0) {
        unsigned long long k = sK[0];
        if (k == 0ull) k = *fkW;
        const int idx = 1023 - (int)(k & 1023ull);
        outF[0] = freqs[(size_t)LASTB * PNUM + idx];
    }
}

// ---------------------------------------------------------------------------
extern "C" void kernel_launch(void* const* d_in, const int* in_sizes, int n_in,
                              void* d_out, int out_size, void* d_ws, size_t ws_size,
                              hipStream_t stream) {
    const float* freqs = (const float*)d_in[0];
    const float* mags  = (const float*)d_in[1];
    const float* W1    = (const float*)d_in[2];
    const float* b1    = (const float*)d_in[3];
    const float* W2    = (const float*)d_in[4];
    const float* b2    = (const float*)d_in[5];
    const float* W3    = (const float*)d_in[6];
    const float* b3    = (const float*)d_in[7];
    float* out = (float*)d_out;

    unsigned long long* ckArr = (unsigned long long*)d_ws;          // 512 keys
    unsigned long long* fkW   = (unsigned long long*)((char*)d_ws + 4096);

    fusedA<<<NBLK, 256, 0, stream>>>(freqs, mags, W1, b1, W2, b2, W3, b3,
                                     out, ckArr, fkW);
    finalize<<<1, 256, 0, stream>>>(freqs, ckArr, fkW, out + (size_t)BP * 8);
}